// Round 6
// baseline (188.831 us; speedup 1.0000x reference)
//
#include <hip/hip_runtime.h>
#include <hip/hip_bf16.h>

// N=16, M=2, T=300, V=25, C=64, KT=9, PAD=4. NM=32, skeletons SK=9600, rows=240000.
// prep -> gcn (1-wave blocks, reg weight frags, 9.2 KB LDS/wave, y ws [nm][v][t][c])
//      -> conv v11: 4000 blocks x 4 waves, 32x32x16 MFMA, wave (wc,wt) owns one
//               32c x 32t tile. rot-swizzle LDS (hi in chunk-bit2) -> conflict-free
//               B-reads; 144 ds_read_b128/block (half of v5). A-layout + C/D epilogue
//               verbatim from the harness-verified v6. h residual loads hoisted.
//
// Workspace: Y (30.72 MB) | WC2 (73.7 KB) | WGT (8 KB) | A2P (2 KB) | SC/SH (256 B each)

typedef __bf16 bf16x8 __attribute__((ext_vector_type(8)));
typedef __bf16 bf16x4 __attribute__((ext_vector_type(4)));
typedef float  f32x4  __attribute__((ext_vector_type(4)));
typedef float  f32x16 __attribute__((ext_vector_type(16)));

#define Y_OFF   0
#define WC2_OFF 30720000
#define WGT_OFF 30793728
#define A2P_OFF 30801920
#define SC_OFF  30803968
#define SH_OFF  30804224

__global__ __launch_bounds__(256) void prep_kernel(
    const float* __restrict__ adj, const float* __restrict__ gcn_w,
    const float* __restrict__ conv_w, const float* __restrict__ conv_b,
    const float* __restrict__ bn_g, const float* __restrict__ bn_b,
    const float* __restrict__ bn_m, const float* __restrict__ bn_v,
    __bf16* __restrict__ wc2, __bf16* __restrict__ wgt,
    __bf16* __restrict__ a2p, float* __restrict__ scale, float* __restrict__ shift) {
  int tid = threadIdx.x;
  // conv weights -> 32x32x16 A-fragment layout (v6-verified):
  // wc2[(g*64 + c)*8 + j] = w[c][ci][kt], g = (kt*4+ks)*2 + hi, ci = ks*16 + hi*8 + j.
  for (int e = blockIdx.x * 256 + tid; e < 36864; e += gridDim.x * 256) {
    int j = e & 7, t1 = e >> 3, c = t1 & 63, g = t1 >> 6;
    int kt = g >> 3, ks = (g >> 1) & 3, hi = g & 1;
    int ci = ks * 16 + hi * 8 + j;
    wc2[e] = (__bf16)conv_w[(c * 64 + ci) * 9 + kt];
  }
  if (blockIdx.x == 0) {
    for (int e = tid; e < 4096; e += 256) {           // wgt[c][k] = gcn_w[k][c]
      int c = e >> 6, k = e & 63;
      wgt[e] = (__bf16)gcn_w[k * 64 + c];
    }
  } else if (blockIdx.x == 1) {
    for (int e = tid; e < 1024; e += 256) {           // A'' 32x32 zero-padded
      int v = e >> 5, u = e & 31;
      float val = 0.f;
      if (v < 25 && u < 25) {
        float dv = 0.f, du = 0.f;
        for (int t = 0; t < 25; ++t) { dv += adj[v * 25 + t]; du += adj[u * 25 + t]; }
        val = rsqrtf(dv) * adj[v * 25 + u] * rsqrtf(du);
      }
      a2p[e] = (__bf16)val;
    }
  } else if (blockIdx.x == 2) {
    if (tid < 64) {
      float sc = bn_g[tid] * rsqrtf(bn_v[tid] + 1e-5f);
      scale[tid] = sc;
      shift[tid] = (conv_b[tid] - bn_m[tid]) * sc + bn_b[tid];
    }
  }
}

// GCN v5 (at HBM floor ~15 µs; untouched): 1-wave blocks (9600), barrier-free.
__global__ __launch_bounds__(64) void gcn_kernel(
    const float* __restrict__ h, const __bf16* __restrict__ wgt_g,
    const __bf16* __restrict__ a2p_g, const float* __restrict__ gcn_b,
    __bf16* __restrict__ y) {
  __shared__ __align__(16) __bf16 hb[2048];           // [u=32][k=64], chunk^(u&7) swizzle
  __shared__ __align__(16) __bf16 x1t[64 * 40];       // [c=64][u] stride 40 (bank rot 20)
  int lane = threadIdx.x;
  int l15 = lane & 15, quad = lane >> 4;
  int skel = blockIdx.x;                              // 9600 blocks
  int nm = skel / 300, tloc = skel - nm * 300;

  // weight fragments from global (same addresses every wave -> L2-hot)
  bf16x8 awg[4][2];
  for (int mt = 0; mt < 4; ++mt)
    for (int kk = 0; kk < 2; ++kk)
      awg[mt][kk] = *(const bf16x8*)&wgt_g[(mt * 16 + l15) * 64 + kk * 32 + quad * 8];
  bf16x8 ba[2];
  for (int nt = 0; nt < 2; ++nt)
    ba[nt] = *(const bf16x8*)&a2p_g[(nt * 16 + l15) * 32 + quad * 8];

  // stage h rows 0..24 (fp32 -> bf16, swizzled), zero rows 25..31
  if (lane < 56) *(uint4*)&hb[1600 + lane * 8] = (uint4){0u, 0u, 0u, 0u};
  for (int it = 0; it < 7; ++it) {
    int u = it * 4 + quad;
    if (u < 25) {
      float4 hv = *(const float4*)&h[(skel * 25 + u) * 64 + l15 * 4];
      bf16x4 b4; b4[0] = (__bf16)hv.x; b4[1] = (__bf16)hv.y; b4[2] = (__bf16)hv.z; b4[3] = (__bf16)hv.w;
      int ch = l15 >> 1;
      *(bf16x4*)&hb[u * 64 + (((ch ^ (u & 7)) * 8) | ((l15 & 1) * 4))] = b4;
    }
  }
  // GEMM1: M=c(64), N=u(32 pad), K=64
  for (int mt = 0; mt < 4; ++mt)
    for (int nt = 0; nt < 2; ++nt) {
      f32x4 acc = {0.f, 0.f, 0.f, 0.f};
      int u = nt * 16 + l15;
      for (int kk = 0; kk < 2; ++kk) {
        bf16x8 b = *(const bf16x8*)&hb[u * 64 + (((kk * 4 + quad) ^ (u & 7)) * 8)];
        acc = __builtin_amdgcn_mfma_f32_16x16x32_bf16(awg[mt][kk], b, acc, 0, 0, 0);
      }
      int c0 = mt * 16 + quad * 4;
      for (int r = 0; r < 4; ++r) x1t[(c0 + r) * 40 + u] = (__bf16)acc[r];
    }
  // GEMM2: M=c(64), N=v(32 pad), K=u(32 pad); epilogue -> ystage (reuse hb, swizzled)
  for (int mt = 0; mt < 4; ++mt)
    for (int nt = 0; nt < 2; ++nt) {
      f32x4 acc = {0.f, 0.f, 0.f, 0.f};
      bf16x8 a = *(const bf16x8*)&x1t[(mt * 16 + l15) * 40 + quad * 8];
      acc = __builtin_amdgcn_mfma_f32_16x16x32_bf16(a, ba[nt], acc, 0, 0, 0);
      int v = nt * 16 + l15, c0 = mt * 16 + quad * 4;
      if (v < 25) {
        float4 bias = *(const float4*)&gcn_b[c0];
        bf16x4 o;
        o[0] = (__bf16)fmaxf(acc[0] + bias.x, 0.f);
        o[1] = (__bf16)fmaxf(acc[1] + bias.y, 0.f);
        o[2] = (__bf16)fmaxf(acc[2] + bias.z, 0.f);
        o[3] = (__bf16)fmaxf(acc[3] + bias.w, 0.f);
        int ch = (c0 >> 3) ^ (v & 7);
        *(bf16x4*)&hb[v * 64 + ((ch * 8) | (c0 & 7))] = o;
      }
    }
  // coalesced store: y[((nm*25+v)*300 + tloc)*64 + c], 25 rows x 128 B
  for (int e = lane; e < 200; e += 64) {
    int v = e >> 3, ch = e & 7;
    uint4 val = *(const uint4*)&hb[v * 64 + ((ch ^ (v & 7)) * 8)];
    *(uint4*)&y[((nm * 25 + v) * 300 + tloc) * 64 + ch * 8] = val;
  }
}

// Conv v11: 4 waves, wave (wc = w&1, wt = w>>1) -> c [wc*32,+32) x t [t0+wt*32,+32).
// K = 576 = 36 steps of 16. Per wave: 36 A-loads (L1-hot) + 36 ds_read_b128 + 36 MFMA.
// rot-swizzle: c-chunk cc stored at pos = ((cc>>1)|((cc&1)<<2)) ^ (r&7)  -- hi lives in
// chunk-bit2, so the {hi=0,hi=1} pair spans distinct bank-group pairs under XOR with
// row: every bank group hit exactly 8x per wave-read => conflict-free (v6's 2.3M
// conflicts came from hi in bit0).
__global__ __launch_bounds__(256, 6) void conv_kernel(
    const __bf16* __restrict__ y, const __bf16* __restrict__ wc2,
    const float* __restrict__ scale, const float* __restrict__ shift,
    const float* __restrict__ h, float* __restrict__ out) {
  __shared__ __align__(16) __bf16 my[72 * 64];        // 72 rows x 64c, rot-swizzled
  int tid = threadIdx.x, w = tid >> 6, lane = tid & 63;
  int l31 = lane & 31, hi = lane >> 5;
  int wc = w & 1, wt = w >> 1;
  int ti = blockIdx.x, vv = blockIdx.y, nm = blockIdx.z;
  int t0 = (ti < 4) ? ti * 64 : 236;                  // last tile overlaps 20 rows (benign)

  { // cooperative stage: 72 rows x 128 B from y[nm][vv][t0-4 .. t0+67][:]
    const __bf16* ybase = &y[((nm * 25 + vv) * 300) * 64];
    uint4 stg[3];
    for (int it = 0; it < 3; ++it) {
      int idx = it * 256 + tid;
      uint4 val = {0u, 0u, 0u, 0u};
      if (idx < 576) {
        int r = idx >> 3, cc = idx & 7, tg = t0 - 4 + r;
        if (tg >= 0 && tg < 300) val = *(const uint4*)&ybase[tg * 64 + cc * 8];
      }
      stg[it] = val;
    }
    for (int it = 0; it < 3; ++it) {
      int idx = it * 256 + tid;
      if (idx < 576) {
        int r = idx >> 3, cc = idx & 7;
        int pos = ((cc >> 1) | ((cc & 1) << 2)) ^ (r & 7);
        *(uint4*)&my[r * 64 + pos * 8] = stg[it];
      }
    }
  }

  // hoist residual loads (addresses known at entry; latency hides under K-loop)
  int cbase = wc * 32 + hi * 4;
  int tt = t0 + wt * 32 + l31;                        // always < 300 by tile choice
  int obase = ((nm * 300 + tt) * 25 + vv) * 64 + cbase;
  float4 hr[4];
#pragma unroll
  for (int q = 0; q < 4; ++q) hr[q] = *(const float4*)&h[obase + q * 8];

  __syncthreads();

  f32x16 acc = {0.f, 0.f, 0.f, 0.f, 0.f, 0.f, 0.f, 0.f,
                0.f, 0.f, 0.f, 0.f, 0.f, 0.f, 0.f, 0.f};

  // A: lane holds w[c = wc*32+l31][ci = ks*16+hi*8+j][kt]; step s = kt*4+ks at
  // aptr + s*1024 (g = s*2+hi folded into base). Both wt-waves of a wc share A -> L1.
  const __bf16* aptr = wc2 + (hi * 64 + wc * 32 + l31) * 8;
  int rbase = wt * 32 + l31;
#pragma unroll
  for (int s = 0; s < 36; ++s) {
    bf16x8 a = *(const bf16x8*)(aptr + s * 1024);
    int row = rbase + (s >> 2);                       // + kt
    bf16x8 b = *(const bf16x8*)&my[row * 64 + ((((s & 3) | (hi << 2)) ^ (row & 7)) * 8)];
    acc = __builtin_amdgcn_mfma_f32_32x32x16_bf16(a, b, acc, 0, 0, 0);
  }

  // C/D layout (v6-verified): col = lane&31 = t, row = (reg&3) + 8*(reg>>2) + 4*hi = c.
#pragma unroll
  for (int q = 0; q < 4; ++q) {
    float4 s4 = *(const float4*)&scale[cbase + q * 8];
    float4 h4 = *(const float4*)&shift[cbase + q * 8];
    float4 o;
    o.x = fmaxf(acc[q * 4 + 0] * s4.x + h4.x, 0.f) + hr[q].x;
    o.y = fmaxf(acc[q * 4 + 1] * s4.y + h4.y, 0.f) + hr[q].y;
    o.z = fmaxf(acc[q * 4 + 2] * s4.z + h4.z, 0.f) + hr[q].z;
    o.w = fmaxf(acc[q * 4 + 3] * s4.w + h4.w, 0.f) + hr[q].w;
    *(float4*)&out[obase + q * 8] = o;
  }
}

extern "C" void kernel_launch(void* const* d_in, const int* in_sizes, int n_in,
                              void* d_out, int out_size, void* d_ws, size_t ws_size,
                              hipStream_t stream) {
  const float* h      = (const float*)d_in[0];
  const float* adj    = (const float*)d_in[1];
  const float* gcn_w  = (const float*)d_in[2];
  const float* gcn_b  = (const float*)d_in[3];
  const float* conv_w = (const float*)d_in[4];
  const float* conv_b = (const float*)d_in[5];
  const float* bn_g   = (const float*)d_in[6];
  const float* bn_b   = (const float*)d_in[7];
  const float* bn_m   = (const float*)d_in[8];
  const float* bn_v   = (const float*)d_in[9];
  float* out = (float*)d_out;
  char* ws = (char*)d_ws;

  __bf16* y_ws   = (__bf16*)(ws + Y_OFF);
  __bf16* wc2    = (__bf16*)(ws + WC2_OFF);
  __bf16* wgt    = (__bf16*)(ws + WGT_OFF);
  __bf16* a2p    = (__bf16*)(ws + A2P_OFF);
  float*  scale  = (float*)(ws + SC_OFF);
  float*  shift  = (float*)(ws + SH_OFF);

  prep_kernel<<<64, 256, 0, stream>>>(adj, gcn_w, conv_w, conv_b, bn_g, bn_b, bn_m, bn_v,
                                      wc2, wgt, a2p, scale, shift);
  gcn_kernel<<<9600, 64, 0, stream>>>(h, wgt, a2p, gcn_b, y_ws);
  conv_kernel<<<dim3(5, 25, 32), 256, 0, stream>>>(y_ws, wc2, scale, shift, h, out);
}

// Round 7
// 185.498 us; speedup vs baseline: 1.0180x; 1.0180x over previous
//
#include <hip/hip_runtime.h>
#include <hip/hip_bf16.h>

// N=16, M=2, T=300, V=25, C=64, KT=9, PAD=4. NM=32, skeletons SK=9600, rows=240000.
// prep -> gcn (1-wave blocks, reg weight frags, 9.2 KB LDS/wave, y ws [nm][v][t][c])
//      -> conv v12: 8000 one-wave blocks (item x t-half), BARRIER-FREE. Wave owns
//               64c x 32t; private 40x64 swizzled LDS tile (5.1 KB); all memory
//               patterns verbatim from verified v5 (A layout, l15/quad B-read, stage
//               swizzle, epilogue). B-frag reused across 4 m-tiles (72 ds_read/item,
//               was 288). 24 independent waves/CU -> decorrelated phases.
//
// Workspace: Y (30.72 MB) | WC2 (73.7 KB) | WGT (8 KB) | A2P (2 KB) | SC/SH (256 B each)

typedef __bf16 bf16x8 __attribute__((ext_vector_type(8)));
typedef __bf16 bf16x4 __attribute__((ext_vector_type(4)));
typedef float  f32x4  __attribute__((ext_vector_type(4)));

#define Y_OFF   0
#define WC2_OFF 30720000
#define WGT_OFF 30793728
#define A2P_OFF 30801920
#define SC_OFF  30803968
#define SH_OFF  30804224

__global__ __launch_bounds__(256) void prep_kernel(
    const float* __restrict__ adj, const float* __restrict__ gcn_w,
    const float* __restrict__ conv_w, const float* __restrict__ conv_b,
    const float* __restrict__ bn_g, const float* __restrict__ bn_b,
    const float* __restrict__ bn_m, const float* __restrict__ bn_v,
    __bf16* __restrict__ wc2, __bf16* __restrict__ wgt,
    __bf16* __restrict__ a2p, float* __restrict__ scale, float* __restrict__ shift) {
  int tid = threadIdx.x;
  // conv weights -> fragment layout: wc2[((kk*4+quad)*64 + c)*8 + j] = w[c][ci][kt],
  // kap = (kk*4+quad)*8 + j = kt*64 + ci (kt-major K index).
  for (int e = blockIdx.x * 256 + tid; e < 36864; e += gridDim.x * 256) {
    int j = e & 7, t1 = e >> 3, c = t1 & 63, g = t1 >> 6;
    int kap = g * 8 + j, kt = kap >> 6, ci = kap & 63;
    wc2[e] = (__bf16)conv_w[(c * 64 + ci) * 9 + kt];
  }
  if (blockIdx.x == 0) {
    for (int e = tid; e < 4096; e += 256) {           // wgt[c][k] = gcn_w[k][c]
      int c = e >> 6, k = e & 63;
      wgt[e] = (__bf16)gcn_w[k * 64 + c];
    }
  } else if (blockIdx.x == 1) {
    for (int e = tid; e < 1024; e += 256) {           // A'' 32x32 zero-padded
      int v = e >> 5, u = e & 31;
      float val = 0.f;
      if (v < 25 && u < 25) {
        float dv = 0.f, du = 0.f;
        for (int t = 0; t < 25; ++t) { dv += adj[v * 25 + t]; du += adj[u * 25 + t]; }
        val = rsqrtf(dv) * adj[v * 25 + u] * rsqrtf(du);
      }
      a2p[e] = (__bf16)val;
    }
  } else if (blockIdx.x == 2) {
    if (tid < 64) {
      float sc = bn_g[tid] * rsqrtf(bn_v[tid] + 1e-5f);
      scale[tid] = sc;
      shift[tid] = (conv_b[tid] - bn_m[tid]) * sc + bn_b[tid];
    }
  }
}

// GCN v5 (at HBM floor ~15 µs; untouched): 1-wave blocks (9600), barrier-free.
__global__ __launch_bounds__(64) void gcn_kernel(
    const float* __restrict__ h, const __bf16* __restrict__ wgt_g,
    const __bf16* __restrict__ a2p_g, const float* __restrict__ gcn_b,
    __bf16* __restrict__ y) {
  __shared__ __align__(16) __bf16 hb[2048];           // [u=32][k=64], chunk^(u&7) swizzle
  __shared__ __align__(16) __bf16 x1t[64 * 40];       // [c=64][u] stride 40 (bank rot 20)
  int lane = threadIdx.x;
  int l15 = lane & 15, quad = lane >> 4;
  int skel = blockIdx.x;                              // 9600 blocks
  int nm = skel / 300, tloc = skel - nm * 300;

  // weight fragments from global (same addresses every wave -> L2-hot)
  bf16x8 awg[4][2];
  for (int mt = 0; mt < 4; ++mt)
    for (int kk = 0; kk < 2; ++kk)
      awg[mt][kk] = *(const bf16x8*)&wgt_g[(mt * 16 + l15) * 64 + kk * 32 + quad * 8];
  bf16x8 ba[2];
  for (int nt = 0; nt < 2; ++nt)
    ba[nt] = *(const bf16x8*)&a2p_g[(nt * 16 + l15) * 32 + quad * 8];

  // stage h rows 0..24 (fp32 -> bf16, swizzled), zero rows 25..31
  if (lane < 56) *(uint4*)&hb[1600 + lane * 8] = (uint4){0u, 0u, 0u, 0u};
  for (int it = 0; it < 7; ++it) {
    int u = it * 4 + quad;
    if (u < 25) {
      float4 hv = *(const float4*)&h[(skel * 25 + u) * 64 + l15 * 4];
      bf16x4 b4; b4[0] = (__bf16)hv.x; b4[1] = (__bf16)hv.y; b4[2] = (__bf16)hv.z; b4[3] = (__bf16)hv.w;
      int ch = l15 >> 1;
      *(bf16x4*)&hb[u * 64 + (((ch ^ (u & 7)) * 8) | ((l15 & 1) * 4))] = b4;
    }
  }
  // GEMM1: M=c(64), N=u(32 pad), K=64
  for (int mt = 0; mt < 4; ++mt)
    for (int nt = 0; nt < 2; ++nt) {
      f32x4 acc = {0.f, 0.f, 0.f, 0.f};
      int u = nt * 16 + l15;
      for (int kk = 0; kk < 2; ++kk) {
        bf16x8 b = *(const bf16x8*)&hb[u * 64 + (((kk * 4 + quad) ^ (u & 7)) * 8)];
        acc = __builtin_amdgcn_mfma_f32_16x16x32_bf16(awg[mt][kk], b, acc, 0, 0, 0);
      }
      int c0 = mt * 16 + quad * 4;
      for (int r = 0; r < 4; ++r) x1t[(c0 + r) * 40 + u] = (__bf16)acc[r];
    }
  // GEMM2: M=c(64), N=v(32 pad), K=u(32 pad); epilogue -> ystage (reuse hb, swizzled)
  for (int mt = 0; mt < 4; ++mt)
    for (int nt = 0; nt < 2; ++nt) {
      f32x4 acc = {0.f, 0.f, 0.f, 0.f};
      bf16x8 a = *(const bf16x8*)&x1t[(mt * 16 + l15) * 40 + quad * 8];
      acc = __builtin_amdgcn_mfma_f32_16x16x32_bf16(a, ba[nt], acc, 0, 0, 0);
      int v = nt * 16 + l15, c0 = mt * 16 + quad * 4;
      if (v < 25) {
        float4 bias = *(const float4*)&gcn_b[c0];
        bf16x4 o;
        o[0] = (__bf16)fmaxf(acc[0] + bias.x, 0.f);
        o[1] = (__bf16)fmaxf(acc[1] + bias.y, 0.f);
        o[2] = (__bf16)fmaxf(acc[2] + bias.z, 0.f);
        o[3] = (__bf16)fmaxf(acc[3] + bias.w, 0.f);
        int ch = (c0 >> 3) ^ (v & 7);
        *(bf16x4*)&hb[v * 64 + ((ch * 8) | (c0 & 7))] = o;
      }
    }
  // coalesced store: y[((nm*25+v)*300 + tloc)*64 + c], 25 rows x 128 B
  for (int e = lane; e < 200; e += 64) {
    int v = e >> 3, ch = e & 7;
    uint4 val = *(const uint4*)&hb[v * 64 + ((ch ^ (v & 7)) * 8)];
    *(uint4*)&y[((nm * 25 + v) * 300 + tloc) * 64 + ch * 8] = val;
  }
}

// Conv v12: 1-wave blocks, barrier-free. bid = item*2 + t-half. Wave: stage private
// 40x64 tile (rows t0-4..t0+35, v5 swizzle), K-loop 18 kk x {2 B ds_reads reused by
// 4 m-tiles, 4 A loads, 8 MFMA}, v5 epilogue per (m,n). All patterns v5-verified.
__global__ __launch_bounds__(64, 6) void conv_kernel(
    const __bf16* __restrict__ y, const __bf16* __restrict__ wc2,
    const float* __restrict__ scale, const float* __restrict__ shift,
    const float* __restrict__ h, float* __restrict__ out) {
  __shared__ __align__(16) __bf16 my[40 * 64];        // 5.1 KB, private to this wave
  int lane = threadIdx.x;
  int l15 = lane & 15, quad = lane >> 4;
  int bid = blockIdx.x;                               // 8000 = 4000 items x 2 halves
  int item = bid >> 1, th = bid & 1;
  int ti = item % 5, rest = item / 5;
  int vv = rest % 25, nm = rest / 25;
  int t0 = ((ti < 4) ? ti * 64 : 236) + th * 32;      // this half's first output row

  { // private stage: 40 rows x 128 B (1 KB coalesced per instr), v5 swizzle
    const __bf16* ybase = &y[((nm * 25 + vv) * 300) * 64];
#pragma unroll
    for (int it = 0; it < 5; ++it) {
      int idx = it * 64 + lane;
      int r = idx >> 3, cc = idx & 7, tg = t0 - 4 + r;
      uint4 val = {0u, 0u, 0u, 0u};
      if (tg >= 0 && tg < 300) val = *(const uint4*)&ybase[tg * 64 + cc * 8];
      *(uint4*)&my[r * 64 + ((cc ^ (r & 7)) * 8)] = val;
    }
  }
  // no __syncthreads: same-wave LDS RAW is ordered by lgkmcnt (gcn relies on this too)

  f32x4 acc[4][2];
#pragma unroll
  for (int m = 0; m < 4; ++m)
#pragma unroll
    for (int n = 0; n < 2; ++n) acc[m][n] = (f32x4){0.f, 0.f, 0.f, 0.f};

#pragma unroll
  for (int kk = 0; kk < 18; ++kk) {
    int kt = kk >> 1, chb = (kk & 1) * 4 + quad;      // v5's verified B pattern
    int r0 = l15 + kt, r1 = 16 + l15 + kt;            // n=0 / n=1 rows (0..39)
    bf16x8 b0 = *(const bf16x8*)&my[r0 * 64 + ((chb ^ (r0 & 7)) * 8)];
    bf16x8 b1 = *(const bf16x8*)&my[r1 * 64 + ((chb ^ (r1 & 7)) * 8)];
#pragma unroll
    for (int m = 0; m < 4; ++m) {
      bf16x8 a = *(const bf16x8*)&wc2[((kk * 4 + quad) * 64 + m * 16 + l15) * 8];
      acc[m][0] = __builtin_amdgcn_mfma_f32_16x16x32_bf16(a, b0, acc[m][0], 0, 0, 0);
      acc[m][1] = __builtin_amdgcn_mfma_f32_16x16x32_bf16(a, b1, acc[m][1], 0, 0, 0);
    }
  }

#pragma unroll
  for (int m = 0; m < 4; ++m) {
    int c0 = m * 16 + quad * 4;
    float4 sc = *(const float4*)&scale[c0];
    float4 sh = *(const float4*)&shift[c0];
#pragma unroll
    for (int n = 0; n < 2; ++n) {
      int tt = t0 + n * 16 + l15;                     // always < 300 by tile choice
      int idx = ((nm * 300 + tt) * 25 + vv) * 64 + c0;
      float4 hr = *(const float4*)&h[idx];
      float4 o;
      o.x = fmaxf(acc[m][n][0] * sc.x + sh.x, 0.f) + hr.x;
      o.y = fmaxf(acc[m][n][1] * sc.y + sh.y, 0.f) + hr.y;
      o.z = fmaxf(acc[m][n][2] * sc.z + sh.z, 0.f) + hr.z;
      o.w = fmaxf(acc[m][n][3] * sc.w + sh.w, 0.f) + hr.w;
      *(float4*)&out[idx] = o;
    }
  }
}

extern "C" void kernel_launch(void* const* d_in, const int* in_sizes, int n_in,
                              void* d_out, int out_size, void* d_ws, size_t ws_size,
                              hipStream_t stream) {
  const float* h      = (const float*)d_in[0];
  const float* adj    = (const float*)d_in[1];
  const float* gcn_w  = (const float*)d_in[2];
  const float* gcn_b  = (const float*)d_in[3];
  const float* conv_w = (const float*)d_in[4];
  const float* conv_b = (const float*)d_in[5];
  const float* bn_g   = (const float*)d_in[6];
  const float* bn_b   = (const float*)d_in[7];
  const float* bn_m   = (const float*)d_in[8];
  const float* bn_v   = (const float*)d_in[9];
  float* out = (float*)d_out;
  char* ws = (char*)d_ws;

  __bf16* y_ws   = (__bf16*)(ws + Y_OFF);
  __bf16* wc2    = (__bf16*)(ws + WC2_OFF);
  __bf16* wgt    = (__bf16*)(ws + WGT_OFF);
  __bf16* a2p    = (__bf16*)(ws + A2P_OFF);
  float*  scale  = (float*)(ws + SC_OFF);
  float*  shift  = (float*)(ws + SH_OFF);

  prep_kernel<<<64, 256, 0, stream>>>(adj, gcn_w, conv_w, conv_b, bn_g, bn_b, bn_m, bn_v,
                                      wc2, wgt, a2p, scale, shift);
  gcn_kernel<<<9600, 64, 0, stream>>>(h, wgt, a2p, gcn_b, y_ws);
  conv_kernel<<<8000, 64, 0, stream>>>(y_ws, wc2, scale, shift, h, out);
}

// Round 9
// 170.715 us; speedup vs baseline: 1.1061x; 1.0866x over previous
//
#include <hip/hip_runtime.h>
#include <hip/hip_bf16.h>

// N=16, M=2, T=300, V=25, C=64, KT=9, PAD=4. NM=32, skeletons SK=9600, rows=240000.
// prep -> gcn (1-wave blocks, reg weight frags, 9.2 KB LDS/wave, y ws [nm][v][t][c])
//      -> conv v13: v10 body byte-identical (4-wave blocks, c-split, reg-staged
//               swizzled 72x64 tile, 16x16x32 MFMA, hoisted residual loads). ONE
//               change: grid = dim3(25,5,32), vv fastest -> the 25 blocks covering
//               all v of one (ti,nm) launch back-to-back, so their 256B-stride-6.4KB
//               h/out accesses merge into contiguous DRAM row coverage.
//   (Round 8 resubmit: round-7 bench failed in the container broker, no data.)
//
// Workspace: Y (30.72 MB) | WC2 (73.7 KB) | WGT (8 KB) | A2P (2 KB) | SC/SH (256 B each)

typedef __bf16 bf16x8 __attribute__((ext_vector_type(8)));
typedef __bf16 bf16x4 __attribute__((ext_vector_type(4)));
typedef float  f32x4  __attribute__((ext_vector_type(4)));

#define Y_OFF   0
#define WC2_OFF 30720000
#define WGT_OFF 30793728
#define A2P_OFF 30801920
#define SC_OFF  30803968
#define SH_OFF  30804224

__global__ __launch_bounds__(256) void prep_kernel(
    const float* __restrict__ adj, const float* __restrict__ gcn_w,
    const float* __restrict__ conv_w, const float* __restrict__ conv_b,
    const float* __restrict__ bn_g, const float* __restrict__ bn_b,
    const float* __restrict__ bn_m, const float* __restrict__ bn_v,
    __bf16* __restrict__ wc2, __bf16* __restrict__ wgt,
    __bf16* __restrict__ a2p, float* __restrict__ scale, float* __restrict__ shift) {
  int tid = threadIdx.x;
  // conv weights -> fragment layout: wc2[((kk*4+quad)*64 + c)*8 + j] = w[c][ci][kt],
  // kap = (kk*4+quad)*8 + j = kt*64 + ci (kt-major K index).
  for (int e = blockIdx.x * 256 + tid; e < 36864; e += gridDim.x * 256) {
    int j = e & 7, t1 = e >> 3, c = t1 & 63, g = t1 >> 6;
    int kap = g * 8 + j, kt = kap >> 6, ci = kap & 63;
    wc2[e] = (__bf16)conv_w[(c * 64 + ci) * 9 + kt];
  }
  if (blockIdx.x == 0) {
    for (int e = tid; e < 4096; e += 256) {           // wgt[c][k] = gcn_w[k][c]
      int c = e >> 6, k = e & 63;
      wgt[e] = (__bf16)gcn_w[k * 64 + c];
    }
  } else if (blockIdx.x == 1) {
    for (int e = tid; e < 1024; e += 256) {           // A'' 32x32 zero-padded
      int v = e >> 5, u = e & 31;
      float val = 0.f;
      if (v < 25 && u < 25) {
        float dv = 0.f, du = 0.f;
        for (int t = 0; t < 25; ++t) { dv += adj[v * 25 + t]; du += adj[u * 25 + t]; }
        val = rsqrtf(dv) * adj[v * 25 + u] * rsqrtf(du);
      }
      a2p[e] = (__bf16)val;
    }
  } else if (blockIdx.x == 2) {
    if (tid < 64) {
      float sc = bn_g[tid] * rsqrtf(bn_v[tid] + 1e-5f);
      scale[tid] = sc;
      shift[tid] = (conv_b[tid] - bn_m[tid]) * sc + bn_b[tid];
    }
  }
}

// GCN v5 (at HBM floor ~15 µs; untouched): 1-wave blocks (9600), barrier-free.
__global__ __launch_bounds__(64) void gcn_kernel(
    const float* __restrict__ h, const __bf16* __restrict__ wgt_g,
    const __bf16* __restrict__ a2p_g, const float* __restrict__ gcn_b,
    __bf16* __restrict__ y) {
  __shared__ __align__(16) __bf16 hb[2048];           // [u=32][k=64], chunk^(u&7) swizzle
  __shared__ __align__(16) __bf16 x1t[64 * 40];       // [c=64][u] stride 40 (bank rot 20)
  int lane = threadIdx.x;
  int l15 = lane & 15, quad = lane >> 4;
  int skel = blockIdx.x;                              // 9600 blocks
  int nm = skel / 300, tloc = skel - nm * 300;

  // weight fragments from global (same addresses every wave -> L2-hot)
  bf16x8 awg[4][2];
  for (int mt = 0; mt < 4; ++mt)
    for (int kk = 0; kk < 2; ++kk)
      awg[mt][kk] = *(const bf16x8*)&wgt_g[(mt * 16 + l15) * 64 + kk * 32 + quad * 8];
  bf16x8 ba[2];
  for (int nt = 0; nt < 2; ++nt)
    ba[nt] = *(const bf16x8*)&a2p_g[(nt * 16 + l15) * 32 + quad * 8];

  // stage h rows 0..24 (fp32 -> bf16, swizzled), zero rows 25..31
  if (lane < 56) *(uint4*)&hb[1600 + lane * 8] = (uint4){0u, 0u, 0u, 0u};
  for (int it = 0; it < 7; ++it) {
    int u = it * 4 + quad;
    if (u < 25) {
      float4 hv = *(const float4*)&h[(skel * 25 + u) * 64 + l15 * 4];
      bf16x4 b4; b4[0] = (__bf16)hv.x; b4[1] = (__bf16)hv.y; b4[2] = (__bf16)hv.z; b4[3] = (__bf16)hv.w;
      int ch = l15 >> 1;
      *(bf16x4*)&hb[u * 64 + (((ch ^ (u & 7)) * 8) | ((l15 & 1) * 4))] = b4;
    }
  }
  // GEMM1: M=c(64), N=u(32 pad), K=64
  for (int mt = 0; mt < 4; ++mt)
    for (int nt = 0; nt < 2; ++nt) {
      f32x4 acc = {0.f, 0.f, 0.f, 0.f};
      int u = nt * 16 + l15;
      for (int kk = 0; kk < 2; ++kk) {
        bf16x8 b = *(const bf16x8*)&hb[u * 64 + (((kk * 4 + quad) ^ (u & 7)) * 8)];
        acc = __builtin_amdgcn_mfma_f32_16x16x32_bf16(awg[mt][kk], b, acc, 0, 0, 0);
      }
      int c0 = mt * 16 + quad * 4;
      for (int r = 0; r < 4; ++r) x1t[(c0 + r) * 40 + u] = (__bf16)acc[r];
    }
  // GEMM2: M=c(64), N=v(32 pad), K=u(32 pad); epilogue -> ystage (reuse hb, swizzled)
  for (int mt = 0; mt < 4; ++mt)
    for (int nt = 0; nt < 2; ++nt) {
      f32x4 acc = {0.f, 0.f, 0.f, 0.f};
      bf16x8 a = *(const bf16x8*)&x1t[(mt * 16 + l15) * 40 + quad * 8];
      acc = __builtin_amdgcn_mfma_f32_16x16x32_bf16(a, ba[nt], acc, 0, 0, 0);
      int v = nt * 16 + l15, c0 = mt * 16 + quad * 4;
      if (v < 25) {
        float4 bias = *(const float4*)&gcn_b[c0];
        bf16x4 o;
        o[0] = (__bf16)fmaxf(acc[0] + bias.x, 0.f);
        o[1] = (__bf16)fmaxf(acc[1] + bias.y, 0.f);
        o[2] = (__bf16)fmaxf(acc[2] + bias.z, 0.f);
        o[3] = (__bf16)fmaxf(acc[3] + bias.w, 0.f);
        int ch = (c0 >> 3) ^ (v & 7);
        *(bf16x4*)&hb[v * 64 + ((ch * 8) | (c0 & 7))] = o;
      }
    }
  // coalesced store: y[((nm*25+v)*300 + tloc)*64 + c], 25 rows x 128 B
  for (int e = lane; e < 200; e += 64) {
    int v = e >> 3, ch = e & 7;
    uint4 val = *(const uint4*)&hb[v * 64 + ((ch ^ (v & 7)) * 8)];
    *(uint4*)&y[((nm * 25 + v) * 300 + tloc) * 64 + ch * 8] = val;
  }
}

// Conv v13: body identical to v10 (= v5 perf, 41.1 µs measured). Only the grid
// mapping changed: vv = blockIdx.x (fastest) so all-25-v groups launch together.
__global__ __launch_bounds__(256, 6) void conv_kernel(
    const __bf16* __restrict__ y, const __bf16* __restrict__ wc2,
    const float* __restrict__ scale, const float* __restrict__ shift,
    const float* __restrict__ h, float* __restrict__ out) {
  __shared__ __align__(16) __bf16 my[72 * 64];        // 72 rows x 64c, XOR-swizzled
  int tid = threadIdx.x, w = tid >> 6, lane = tid & 63;
  int l15 = lane & 15, quad = lane >> 4;
  int vv = blockIdx.x, ti = blockIdx.y, nm = blockIdx.z;   // vv fastest (ONLY change)
  int t0 = (ti < 4) ? ti * 64 : 236;                  // last tile overlaps 20 rows (benign)

  { // cooperative stage: 72 rows x 128 B from y[nm][vv][t0-4 .. t0+67][:]
    const __bf16* ybase = &y[((nm * 25 + vv) * 300) * 64];
    uint4 stg[3];
    for (int it = 0; it < 3; ++it) {
      int idx = it * 256 + tid;
      uint4 val = {0u, 0u, 0u, 0u};
      if (idx < 576) {
        int r = idx >> 3, ch = idx & 7, tg = t0 - 4 + r;
        if (tg >= 0 && tg < 300) val = *(const uint4*)&ybase[tg * 64 + ch * 8];
      }
      stg[it] = val;
    }
    for (int it = 0; it < 3; ++it) {
      int idx = it * 256 + tid;
      if (idx < 576) {
        int r = idx >> 3, ch = idx & 7;
        *(uint4*)&my[r * 64 + ((ch ^ (r & 7)) * 8)] = stg[it];
      }
    }
  }

  // hoist epilogue residual loads: addresses known at tile entry; latency hides
  // under the barrier wait + K-loop (~700 cyc of MFMA).
  int c0 = w * 16 + quad * 4;
  float4 hr[4];
#pragma unroll
  for (int n = 0; n < 4; ++n) {
    int tt = t0 + n * 16 + l15;                       // always < 300 by tile choice
    hr[n] = *(const float4*)&h[((nm * 300 + tt) * 25 + vv) * 64 + c0];
  }

  __syncthreads();

  f32x4 acc[4];
#pragma unroll
  for (int n = 0; n < 4; ++n) acc[n] = (f32x4){0.f, 0.f, 0.f, 0.f};

  // 4-deep rolling A-frag prefetch; fully unrolled -> static indices.
  bf16x8 a[4];
#pragma unroll
  for (int p = 0; p < 4; ++p)
    a[p] = *(const bf16x8*)&wc2[((p * 4 + quad) * 64 + w * 16 + l15) * 8];
#pragma unroll
  for (int kk = 0; kk < 18; ++kk) {
    bf16x8 areg = a[kk & 3];
    int kt = kk >> 1, chb = (kk & 1) * 4 + quad;
#pragma unroll
    for (int n = 0; n < 4; ++n) {
      int row = n * 16 + l15 + kt;
      bf16x8 b = *(const bf16x8*)&my[row * 64 + ((chb ^ (row & 7)) * 8)];
      acc[n] = __builtin_amdgcn_mfma_f32_16x16x32_bf16(areg, b, acc[n], 0, 0, 0);
    }
    if (kk + 4 < 18)
      a[kk & 3] = *(const bf16x8*)&wc2[(((kk + 4) * 4 + quad) * 64 + w * 16 + l15) * 8];
  }

  float4 sc = *(const float4*)&scale[c0];
  float4 sh = *(const float4*)&shift[c0];
#pragma unroll
  for (int n = 0; n < 4; ++n) {
    int tt = t0 + n * 16 + l15;
    int idx = ((nm * 300 + tt) * 25 + vv) * 64 + c0;
    float4 o;
    o.x = fmaxf(acc[n][0] * sc.x + sh.x, 0.f) + hr[n].x;
    o.y = fmaxf(acc[n][1] * sc.y + sh.y, 0.f) + hr[n].y;
    o.z = fmaxf(acc[n][2] * sc.z + sh.z, 0.f) + hr[n].z;
    o.w = fmaxf(acc[n][3] * sc.w + sh.w, 0.f) + hr[n].w;
    *(float4*)&out[idx] = o;
  }
}

extern "C" void kernel_launch(void* const* d_in, const int* in_sizes, int n_in,
                              void* d_out, int out_size, void* d_ws, size_t ws_size,
                              hipStream_t stream) {
  const float* h      = (const float*)d_in[0];
  const float* adj    = (const float*)d_in[1];
  const float* gcn_w  = (const float*)d_in[2];
  const float* gcn_b  = (const float*)d_in[3];
  const float* conv_w = (const float*)d_in[4];
  const float* conv_b = (const float*)d_in[5];
  const float* bn_g   = (const float*)d_in[6];
  const float* bn_b   = (const float*)d_in[7];
  const float* bn_m   = (const float*)d_in[8];
  const float* bn_v   = (const float*)d_in[9];
  float* out = (float*)d_out;
  char* ws = (char*)d_ws;

  __bf16* y_ws   = (__bf16*)(ws + Y_OFF);
  __bf16* wc2    = (__bf16*)(ws + WC2_OFF);
  __bf16* wgt    = (__bf16*)(ws + WGT_OFF);
  __bf16* a2p    = (__bf16*)(ws + A2P_OFF);
  float*  scale  = (float*)(ws + SC_OFF);
  float*  shift  = (float*)(ws + SH_OFF);

  prep_kernel<<<64, 256, 0, stream>>>(adj, gcn_w, conv_w, conv_b, bn_g, bn_b, bn_m, bn_v,
                                      wc2, wgt, a2p, scale, shift);
  gcn_kernel<<<9600, 64, 0, stream>>>(h, wgt, a2p, gcn_b, y_ws);
  conv_kernel<<<dim3(25, 5, 32), 256, 0, stream>>>(y_ws, wc2, scale, shift, h, out);
}